// Round 8
// baseline (345.683 us; speedup 1.0000x reference)
//
#include <hip/hip_runtime.h>
#include <stdint.h>

// No implicit FMA contraction: the JAX eager reference has none across ops;
// where XLA fuses we write fmaf() explicitly.
#pragma clang fp contract(off)

#define PDIM 162
#define NW   (2*PDIM*PDIM*3)   // 157464 words, 1.26 MB per bitboard
#define OD   160
#define OD2  (160*160)
#define OD3  (160*160*160)
#define NOUT (2*OD3)

// LDS tile: 24 z-rows x 24 y-rows x 3 words, z parity-grouped, pitch 73 u64
// (146 dwords == 18 mod 32 -> subfield lane stride (Dlz=2 -> D=73 u64) hits
// bank+18 -> 2-way aliasing only = free per m136).
#define PY 73
#define LZI(lz) ((((lz) & 1) * 12) + ((lz) >> 1))
#define LADDR(lz,ly) (LZI(lz) * PY + (ly) * 3)

// ---------------- threefry2x32, JAX partitionable scheme --------------------
__device__ __forceinline__ uint32_t rotl32(uint32_t x, uint32_t r) {
  return (x << r) | (x >> (32u - r));
}

__device__ __forceinline__ uint32_t threefry_bits(uint32_t idx) {
  const uint32_t ks0 = 0u, ks1 = 42u, ks2 = 0x1BD11BDAu ^ 0u ^ 42u;
  uint32_t x0 = 0u + ks0;
  uint32_t x1 = idx + ks1;
#define TFR(r) { x0 += x1; x1 = rotl32(x1, (r)); x1 ^= x0; }
  TFR(13u) TFR(15u) TFR(26u) TFR(6u)
  x0 += ks1; x1 += ks2 + 1u;
  TFR(17u) TFR(29u) TFR(16u) TFR(24u)
  x0 += ks2; x1 += ks0 + 2u;
  TFR(13u) TFR(15u) TFR(26u) TFR(6u)
  x0 += ks0; x1 += ks1 + 3u;
  TFR(17u) TFR(29u) TFR(16u) TFR(24u)
  x0 += ks1; x1 += ks2 + 4u;
  TFR(13u) TFR(15u) TFR(26u) TFR(6u)
  x0 += ks2; x1 += ks0 + 5u;
#undef TFR
  return x0 ^ x1;
}

// ------------- XLA-CPU (Cephes) float32 log replication ---------------------
__device__ __forceinline__ float xla_logf(float xin) {
  uint32_t bits = __float_as_uint(xin);
  float e = (float)((int)(bits >> 23) - 126);
  float x = __uint_as_float((bits & 0x007fffffu) | 0x3f000000u);
  const float SQRTHF = 0.707106781186547524f;
  bool lt = (x < SQRTHF);
  float tmp = lt ? x : 0.0f;
  e = e - (lt ? 1.0f : 0.0f);
  x = x - 1.0f;
  x = x + tmp;
  float z = x * x;
  float y = 7.0376836292e-2f;
  y = fmaf(y, x, -1.1514610310e-1f);
  y = fmaf(y, x,  1.1676998740e-1f);
  y = fmaf(y, x, -1.2420140846e-1f);
  y = fmaf(y, x,  1.4249322787e-1f);
  y = fmaf(y, x, -1.6668057665e-1f);
  y = fmaf(y, x,  2.0000714765e-1f);
  y = fmaf(y, x, -2.4999993993e-1f);
  y = fmaf(y, x,  3.3333331174e-1f);
  y = y * x;
  y = y * z;
  y = fmaf(e, -2.12194440e-4f, y);
  y = fmaf(-0.5f, z, y);
  x = x + y;
  x = fmaf(e, 0.693359375f, x);
  return x;
}

__device__ __forceinline__ float xla_log1pf(float x) {
  float for_large = xla_logf(x + 1.0f);
  float for_small = fmaf(-0.5f, x, 1.0f) * x;
  return (fabsf(x) < 1e-4f) ? for_small : for_large;
}

// ---------------------------- binarize --------------------------------------
__global__ __launch_bounds__(256) void k_binarize(const float* __restrict__ in,
                                                  uint64_t* __restrict__ bits) {
  uint32_t t = blockIdx.x * 256u + threadIdx.x;
  uint32_t w = t >> 6, lane = t & 63u;
  if (w >= (uint32_t)NW) return;          // wave-uniform
  uint32_t row = w / 3u, wx = w - row * 3u;
  uint32_t n  = row / (uint32_t)(PDIM * PDIM);
  uint32_t rr = row - n * (uint32_t)(PDIM * PDIM);
  uint32_t z  = rr / (uint32_t)PDIM;
  uint32_t y  = rr - z * (uint32_t)PDIM;
  uint32_t x  = wx * 64u + lane;
  bool pred = false;
  // pad voxels are provably 0: |0.33*noise| <= 6.08 < 18.42 = |log alpha(0)|
  if ((z - 1u) < 160u && (y - 1u) < 160u && (x - 1u) < 160u) {
    float v = in[((n * 160u + (z - 1u)) * 160u + (y - 1u)) * 160u + (x - 1u)];
    uint32_t i = row * 162u + x;          // flat padded index for RNG
    uint32_t b = threefry_bits(i);
    float f  = __uint_as_float((b >> 9) | 0x3f800000u) - 1.0f;
    float uu = fmaxf(1e-8f, f + 1e-8f);
    float la = xla_logf((v + 1e-8f) / ((1.0f - v) + 1e-8f));
    float noise = xla_logf(uu) - xla_log1pf(-uu);
    float zs = la + noise * 0.33f;
    pred = (zs > 1.1920928955078125e-7f); // logistic>0.5 iff z>2^-23
  }
  uint64_t m = __ballot(pred);
  if (lane == 0) bits[w] = m;
}

// ------------- per-word neighborhood from LDS row triples -------------------
#define NB(dz,dy,dx) ((dx)==-1 ? Lb[(dz)+1][(dy)+1] : ((dx)==1 ? Rb[(dz)+1][(dy)+1] : Vv[(dz)+1][(dy)+1]))

#define GATHER_W(SRC, lz, ly, w) \
  _Pragma("unroll") \
  for (int dz = 0; dz < 3; ++dz) \
    _Pragma("unroll") \
    for (int dy = 0; dy < 3; ++dy) { \
      int rb = LADDR((lz) + dz - 1, (ly) + dy - 1); \
      uint64_t r0 = SRC[rb], r1 = SRC[rb + 1], r2 = SRC[rb + 2]; \
      uint64_t b = ((w) == 0) ? r0 : (((w) == 1) ? r1 : r2); \
      uint64_t a = ((w) == 0) ? 0ull : (((w) == 1) ? r0 : r1); \
      uint64_t d = ((w) == 0) ? r1 : (((w) == 1) ? r2 : 0ull); \
      Vv[dz][dy] = b; \
      Lb[dz][dy] = (b << 1) | (a >> 63); \
      Rb[dz][dy] = (b >> 1) | (d << 63); \
    }

// ---------------------------- iteration kernel ------------------------------
// One block: 8x8 (z,y) core x full 192-bit x, halo 8 -> 24x24 LDS tile.
// 800 blocks -> ~3 co-resident blocks/CU hide intra-block phase latency.
__global__ __launch_bounds__(256) void k_iter(const uint64_t* __restrict__ bin,
                                              uint64_t* __restrict__ bout,
                                              int zero_pads) {
  __shared__ uint64_t Bt[1752];
  __shared__ uint64_t Ge[1752];
  const int tid = threadIdx.x;
  const int bid = blockIdx.x;
  const int n  = bid / 400;
  const int rm = bid - n * 400;
  const int tz = rm / 20, ty = rm - tz * 20;
  const int gz0 = 1 + 8 * tz, gy0 = 1 + 8 * ty;   // both odd

  // Zero bout's pad rows (z or y in {0,161}) once per call (block 0, iter 1).
  if (zero_pads && bid == 0) {
    for (int j = tid; j < 1288; j += 256) {
      int nn, z, y;
      if (j < 648) { nn = j / 324; int r = j - nn * 324;
                     z = (r >= 162) ? 161 : 0; y = (r >= 162) ? r - 162 : r; }
      else { int j2 = j - 648; nn = j2 / 320; int r = j2 - nn * 320;
             y = (r >= 160) ? 161 : 0; z = 1 + ((r >= 160) ? r - 160 : r); }
      uint64_t* p = bout + (((nn * 162 + z) * 162) + y) * 3;
      p[0] = 0; p[1] = 0; p[2] = 0;
    }
  }

  // ---- load tile + halo 8 (w,ly fastest -> coalesced global reads) ----
  for (int ti = tid; ti < 24 * 24 * 3; ti += 256) {
    int w = ti % 3, r = ti / 3, ly = r % 24, lz = r / 24;
    int z = gz0 - 8 + lz, y = gy0 - 8 + ly;
    uint64_t v = 0;
    if ((unsigned)z < 162u && (unsigned)y < 162u)
      v = bin[((n * 162 + z) * 162 + y) * 3 + w];
    Bt[LADDR(lz, ly) + w] = v;
  }
  __syncthreads();

  // ---- ge2 (C26>=2, not-endpoint) on halo 7 (22x22), iteration-start state
  for (int ti = tid; ti < 22 * 22 * 3; ti += 256) {
    int w = ti % 3, r = ti / 3, iz = r % 22, iy = r / 22;
    int lz = 1 + iz, ly = 1 + iy;
    int base = LADDR(lz, ly) + w;
    uint64_t res = 0;
    if (Bt[base] != 0ull) {               // ge2 only consumed ANDed with center
      uint64_t Vv[3][3], Lb[3][3], Rb[3][3];
      GATHER_W(Bt, lz, ly, w)
      uint64_t s = 0, c = 0;
#define ACC(bb) { uint64_t _b = (bb); c |= s & _b; s |= _b; }
#pragma unroll
      for (int dz = -1; dz <= 1; ++dz)
#pragma unroll
        for (int dy = -1; dy <= 1; ++dy) {
          ACC(NB(dz,dy,-1)); ACC(NB(dz,dy,1));
          if (dz != 0 || dy != 0) ACC(NB(dz,dy,0));
        }
#undef ACC
      res = c;
    }
    Ge[base] = res;
  }
  __syncthreads();

  // ---- 8 subfield passes, halo 7-k; lane stride Dlz=2 -> bank+18 (free) ---
  const int PLZ[8] = {1,0,1,0,1,0,1,0};   // lz parity (xo=0 -> z even -> lz odd)
  const int PLY[8] = {1,1,0,0,1,1,0,0};   // ly parity
  for (int k = 0; k < 8; ++k) {
    const int h = 7 - k, cnt = 4 + h;     // parity-elements per dim
    const uint64_t xmask = (k < 4) ? 0x5555555555555555ull : 0xAAAAAAAAAAAAAAAAull;
    int s0 = 8 - h;
    const int slz = s0 + ((s0 ^ PLZ[k]) & 1);
    const int sly = s0 + ((s0 ^ PLY[k]) & 1);
    for (int ti = tid; ti < cnt * cnt * 3; ti += 256) {
      int w = ti % 3, r = ti / 3, iz = r % cnt, iy = r / cnt;
      int lz = slz + 2 * iz, ly = sly + 2 * iy;
      int base = LADDR(lz, ly) + w;
      uint64_t center = Bt[base];
      uint64_t active = center & xmask & Ge[base];
      if (active == 0ull) continue;
      uint64_t Vv[3][3], Lb[3][3], Rb[3][3];
      GATHER_W(Bt, lz, ly, w)

      // C6 exact 3-bit counter over the 6 faces
      uint64_t on = 0, tw = 0, fo = 0;
#define C6ADD(b) { uint64_t _u = on & (b); on ^= (b); uint64_t _v = tw & _u; tw ^= _u; fo |= _v; }
      C6ADD(NB(-1,0,0)) C6ADD(NB(1,0,0)) C6ADD(NB(0,-1,0))
      C6ADD(NB(0,1,0))  C6ADD(NB(0,0,-1)) C6ADD(NB(0,0,1))
#undef C6ADD
      uint64_t c6eq5 = fo & on & ~tw;
      uint64_t c6le4 = ~(fo & (on | tw));

      // carry-save ==1 detectors over 18 then 26 neighbors
      uint64_t s = 0, c2 = 0;
#define CS(b) { uint64_t _b = (b); c2 |= s & _b; s |= _b; }
      CS(NB(-1,0,0)) CS(NB(1,0,0)) CS(NB(0,-1,0)) CS(NB(0,1,0)) CS(NB(0,0,-1)) CS(NB(0,0,1))
      CS(NB(-1,-1,0)) CS(NB(-1,1,0)) CS(NB(-1,0,-1)) CS(NB(-1,0,1))
      CS(NB(1,-1,0))  CS(NB(1,1,0))  CS(NB(1,0,-1))  CS(NB(1,0,1))
      CS(NB(0,-1,-1)) CS(NB(0,-1,1)) CS(NB(0,1,-1))  CS(NB(0,1,1))
      uint64_t e18 = s & ~c2;
      CS(NB(-1,-1,-1)) CS(NB(-1,-1,1)) CS(NB(-1,1,-1)) CS(NB(-1,1,1))
      CS(NB(1,-1,-1))  CS(NB(1,-1,1))  CS(NB(1,1,-1))  CS(NB(1,1,1))
      uint64_t e26 = s & ~c2;
#undef CS

      // B: corner set with its 6 octant face/edge cells all clear
      uint64_t badB = 0;
#pragma unroll
      for (int sz = -1; sz <= 1; sz += 2)
#pragma unroll
        for (int sy = -1; sy <= 1; sy += 2)
#pragma unroll
          for (int sx = -1; sx <= 1; sx += 2) {
            uint64_t oct = NB(sz,0,0) | NB(0,sy,0) | NB(0,0,sx)
                         | NB(sz,sy,0) | NB(sz,0,sx) | NB(0,sy,sx);
            badB |= NB(sz,sy,sx) & ~oct;
          }
      uint64_t b0ok = ~badB;

      // A: face clear with its full 4-cell in-plane ring set
      uint64_t badA = 0;
      badA |= ~NB(-1,0,0) & NB(-1,-1,0) & NB(-1,1,0) & NB(-1,0,-1) & NB(-1,0,1);
      badA |= ~NB( 1,0,0) & NB( 1,-1,0) & NB( 1,1,0) & NB( 1,0,-1) & NB( 1,0,1);
      badA |= ~NB(0,-1,0) & NB(-1,-1,0) & NB(1,-1,0) & NB(0,-1,-1) & NB(0,-1,1);
      badA |= ~NB(0, 1,0) & NB(-1, 1,0) & NB(1, 1,0) & NB(0, 1,-1) & NB(0, 1,1);
      badA |= ~NB(0,0,-1) & NB(-1,0,-1) & NB(1,0,-1) & NB(0,-1,-1) & NB(0,1,-1);
      badA |= ~NB(0,0, 1) & NB(-1,0, 1) & NB(1,0, 1) & NB(0,-1, 1) & NB(0,1, 1);
      uint64_t a0ok = ~badA;

      uint64_t simple = c6eq5 | e26 | (e18 & b0ok) | (c6le4 & a0ok & b0ok);
      uint64_t del = simple & active;
      if (del) Bt[base] = center & ~del;
      // readers only consume non-updated-parity bits; tearing-safe (R5 arg)
    }
    __syncthreads();
  }

  // ---- write core words back (disjoint across blocks) ----
  for (int ti = tid; ti < 8 * 8 * 3; ti += 256) {
    int w = ti % 3, r = ti / 3, iy = r % 8, iz = r / 8;
    bout[((n * 162 + gz0 + iz) * 162 + (gy0 + iy)) * 3 + w] =
        Bt[LADDR(8 + iz, 8 + iy) + w];
  }
}

// ---------------------------- output ----------------------------------------
__global__ __launch_bounds__(256) void k_output(const uint64_t* __restrict__ bits,
                                                float4* __restrict__ out) {
  uint32_t t = blockIdx.x * 256u + threadIdx.x;
  if (t >= (uint32_t)(NOUT / 4)) return;
  uint32_t i = t * 4u;
  uint32_t n = i / (uint32_t)OD3;
  uint32_t r = i - n * (uint32_t)OD3;
  uint32_t z = r / (uint32_t)OD2; r -= z * (uint32_t)OD2;
  uint32_t y = r / (uint32_t)OD;
  uint32_t x = r - y * (uint32_t)OD;
  uint32_t row = (n * 162u + z + 1u) * 162u + (y + 1u);
  uint32_t bi = x + 1u;
  uint32_t wx = bi >> 6, sft = bi & 63u;
  uint64_t v = bits[row * 3u + wx] >> sft;
  if (sft > 60u) v |= bits[row * 3u + wx + 1u] << (64u - sft);
  out[t] = make_float4((float)(v & 1u), (float)((v >> 1) & 1u),
                       (float)((v >> 2) & 1u), (float)((v >> 3) & 1u));
}

// ---------------------------- launcher --------------------------------------
extern "C" void kernel_launch(void* const* d_in, const int* in_sizes, int n_in,
                              void* d_out, int out_size, void* d_ws, size_t ws_size,
                              hipStream_t stream) {
  const float* in = (const float*)d_in[0];
  float4* out = (float4*)d_out;
  uint64_t* A = (uint64_t*)d_ws;          // bitboard A
  uint64_t* B = A + NW;                   // bitboard B

  k_binarize<<<dim3((NW * 64 + 255) / 256), dim3(256), 0, stream>>>(in, A);
  k_iter<<<dim3(800), dim3(256), 0, stream>>>(A, B, 1);  // iter 1 (+zero B pads)
  k_iter<<<dim3(800), dim3(256), 0, stream>>>(B, A, 0);  // iter 2
  k_iter<<<dim3(800), dim3(256), 0, stream>>>(A, B, 0);  // iter 3
  k_iter<<<dim3(800), dim3(256), 0, stream>>>(B, A, 0);  // iter 4
  k_iter<<<dim3(800), dim3(256), 0, stream>>>(A, B, 0);  // iter 5
  k_output<<<dim3((NOUT / 4 + 255) / 256), dim3(256), 0, stream>>>(B, out);
}

// Round 9
// 273.633 us; speedup vs baseline: 1.2633x; 1.2633x over previous
//
#include <hip/hip_runtime.h>
#include <stdint.h>

// No implicit FMA contraction: the JAX eager reference has none across ops;
// where XLA fuses we write fmaf() explicitly.
#pragma clang fp contract(off)

#define PDIM 162
#define NW   (2*PDIM*PDIM*3)   // 157464 words, 1.26 MB per bitboard
#define OD   160

// LDS tile: 16 z-rows x 16 y-rows x 3 words, flat addr lz*49 + ly*3 + w.
// 49 u64 = 98 dwords == 2 mod 32 -> ge2 lane stride (Dlz=1) is 2-way (free);
// subfield lane stride (Dlz=2) is 4-way (1.58x) on a minority of accesses.
#define PLZP 49
#define LADDR(lz,ly) ((lz)*PLZP + (ly)*3)

// ---------------- threefry2x32, JAX partitionable scheme --------------------
__device__ __forceinline__ uint32_t rotl32(uint32_t x, uint32_t r) {
  return (x << r) | (x >> (32u - r));
}

__device__ __forceinline__ uint32_t threefry_bits(uint32_t idx) {
  const uint32_t ks0 = 0u, ks1 = 42u, ks2 = 0x1BD11BDAu ^ 0u ^ 42u;
  uint32_t x0 = 0u + ks0;
  uint32_t x1 = idx + ks1;
#define TFR(r) { x0 += x1; x1 = rotl32(x1, (r)); x1 ^= x0; }
  TFR(13u) TFR(15u) TFR(26u) TFR(6u)
  x0 += ks1; x1 += ks2 + 1u;
  TFR(17u) TFR(29u) TFR(16u) TFR(24u)
  x0 += ks2; x1 += ks0 + 2u;
  TFR(13u) TFR(15u) TFR(26u) TFR(6u)
  x0 += ks0; x1 += ks1 + 3u;
  TFR(17u) TFR(29u) TFR(16u) TFR(24u)
  x0 += ks1; x1 += ks2 + 4u;
  TFR(13u) TFR(15u) TFR(26u) TFR(6u)
  x0 += ks2; x1 += ks0 + 5u;
#undef TFR
  return x0 ^ x1;
}

// ------------- XLA-CPU (Cephes) float32 log replication ---------------------
__device__ __forceinline__ float xla_logf(float xin) {
  uint32_t bits = __float_as_uint(xin);
  float e = (float)((int)(bits >> 23) - 126);
  float x = __uint_as_float((bits & 0x007fffffu) | 0x3f000000u);
  const float SQRTHF = 0.707106781186547524f;
  bool lt = (x < SQRTHF);
  float tmp = lt ? x : 0.0f;
  e = e - (lt ? 1.0f : 0.0f);
  x = x - 1.0f;
  x = x + tmp;
  float z = x * x;
  float y = 7.0376836292e-2f;
  y = fmaf(y, x, -1.1514610310e-1f);
  y = fmaf(y, x,  1.1676998740e-1f);
  y = fmaf(y, x, -1.2420140846e-1f);
  y = fmaf(y, x,  1.4249322787e-1f);
  y = fmaf(y, x, -1.6668057665e-1f);
  y = fmaf(y, x,  2.0000714765e-1f);
  y = fmaf(y, x, -2.4999993993e-1f);
  y = fmaf(y, x,  3.3333331174e-1f);
  y = y * x;
  y = y * z;
  y = fmaf(e, -2.12194440e-4f, y);
  y = fmaf(-0.5f, z, y);
  x = x + y;
  x = fmaf(e, 0.693359375f, x);
  return x;
}

__device__ __forceinline__ float xla_log1pf(float x) {
  float for_large = xla_logf(x + 1.0f);
  float for_small = fmaf(-0.5f, x, 1.0f) * x;
  return (fabsf(x) < 1e-4f) ? for_small : for_large;
}

// ---------------------------- binarize --------------------------------------
// One block per (n,z,y) row: 192 threads = 3 waves, wave w packs word w via
// ballot. Row decomposition is wave-uniform -> scalar unit, no VALU divides.
__global__ __launch_bounds__(192) void k_binarize(const float* __restrict__ in,
                                                  uint64_t* __restrict__ bits) {
  const uint32_t row = blockIdx.x;               // 0..52487
  const uint32_t n  = row / (uint32_t)(PDIM * PDIM);
  const uint32_t rr = row - n * (uint32_t)(PDIM * PDIM);
  const uint32_t z  = rr / (uint32_t)PDIM;
  const uint32_t y  = rr - z * (uint32_t)PDIM;
  const uint32_t x  = threadIdx.x;               // == w*64 + lane
  bool pred = false;
  // pad voxels are provably 0: |0.33*noise| <= 6.08 < 18.42 = |log alpha(0)|
  if ((z - 1u) < 160u && (y - 1u) < 160u && (x - 1u) < 160u) {
    float v = in[((n * 160u + (z - 1u)) * 160u + (y - 1u)) * 160u + (x - 1u)];
    uint32_t i = row * 162u + x;                 // flat padded index for RNG
    uint32_t b = threefry_bits(i);
    float f  = __uint_as_float((b >> 9) | 0x3f800000u) - 1.0f;
    float uu = fmaxf(1e-8f, f + 1e-8f);
    float la = xla_logf((v + 1e-8f) / ((1.0f - v) + 1e-8f));
    float noise = xla_logf(uu) - xla_log1pf(-uu);
    float zs = la + noise * 0.33f;
    pred = (zs > 1.1920928955078125e-7f);        // logistic>0.5 iff z>2^-23
  }
  uint64_t m = __ballot(pred);
  if ((threadIdx.x & 63u) == 0u)
    bits[row * 3u + (threadIdx.x >> 6)] = m;
}

// ------------- per-word neighborhood from LDS row triples -------------------
#define NB(dz,dy,dx) ((dx)==-1 ? Lb[(dz)+1][(dy)+1] : ((dx)==1 ? Rb[(dz)+1][(dy)+1] : Vv[(dz)+1][(dy)+1]))

#define GATHER_W(SRC, lz, ly, w) \
  _Pragma("unroll") \
  for (int dz = 0; dz < 3; ++dz) \
    _Pragma("unroll") \
    for (int dy = 0; dy < 3; ++dy) { \
      int rb = LADDR((lz) + dz - 1, (ly) + dy - 1); \
      uint64_t r0 = SRC[rb], r1 = SRC[rb + 1], r2 = SRC[rb + 2]; \
      uint64_t b = ((w) == 0) ? r0 : (((w) == 1) ? r1 : r2); \
      uint64_t a = ((w) == 0) ? 0ull : (((w) == 1) ? r0 : r1); \
      uint64_t d = ((w) == 0) ? r1 : (((w) == 1) ? r2 : 0ull); \
      Vv[dz][dy] = b; \
      Lb[dz][dy] = (b << 1) | (a >> 63); \
      Rb[dz][dy] = (b >> 1) | (d << 63); \
    }

// ---------------------------- half-iteration kernel -------------------------
// 8x8 (z,y) core x full 192-bit x, halo 4 -> 16x16 LDS tile (12.5 KB).
// k0==0: compute ge2 (iteration-start) on halo 3, store core ge2 to gge,
//        run subfield passes 0-3 (shrinking halo 3,2,1,0).
// k0==4: load gge (iteration-start) halo 3, run passes 4-7.
// Epilogue: write core state to dst, or (final) float output from LDS.
__global__ __launch_bounds__(256) void k_half(const uint64_t* __restrict__ src,
                                              uint64_t* __restrict__ dst,
                                              uint64_t* __restrict__ gge,
                                              float4* __restrict__ outf,
                                              int k0, int zero_pads) {
  __shared__ uint64_t Bt[16 * PLZP];
  __shared__ uint64_t Ge[16 * PLZP];
  const int tid = threadIdx.x;
  const int bid = blockIdx.x;
  const int n  = bid / 400;
  const int rm = bid - n * 400;
  const int tz = rm / 20, ty = rm - tz * 20;
  const int gz0 = 1 + 8 * tz, gy0 = 1 + 8 * ty;  // both odd

  // Zero dst's pad rows (z or y in {0,161}) once per replay (block 0, S1#1).
  if (zero_pads && bid == 0) {
    for (int j = tid; j < 1288; j += 256) {
      int nn, z, y;
      if (j < 648) { nn = j / 324; int r = j - nn * 324;
                     z = (r >= 162) ? 161 : 0; y = (r >= 162) ? r - 162 : r; }
      else { int j2 = j - 648; nn = j2 / 320; int r = j2 - nn * 320;
             y = (r >= 160) ? 161 : 0; z = 1 + ((r >= 160) ? r - 160 : r); }
      uint64_t* p = dst + (((nn * 162 + z) * 162) + y) * 3;
      p[0] = 0; p[1] = 0; p[2] = 0;
    }
  }

  // ---- load state tile + halo 4 ----
  for (int ti = tid; ti < 16 * 16 * 3; ti += 256) {
    int w = ti % 3, r = ti / 3, ly = r % 16, lz = r / 16;
    int z = gz0 - 4 + lz, y = gy0 - 4 + ly;
    uint64_t v = 0;
    if ((unsigned)z < 162u && (unsigned)y < 162u)
      v = src[((n * 162 + z) * 162 + y) * 3 + w];
    Bt[LADDR(lz, ly) + w] = v;
  }

  if (k0 == 0) {
    __syncthreads();
    // ge2 (C26>=2, not-endpoint) on halo 3 (14x14), iteration-start state
    for (int ti = tid; ti < 14 * 14 * 3; ti += 256) {
      int w = ti % 3, r = ti / 3, iz = r % 14, iy = r / 14;
      int lz = 1 + iz, ly = 1 + iy;
      int base = LADDR(lz, ly) + w;
      uint64_t res = 0;
      if (Bt[base] != 0ull) {            // ge2 only consumed ANDed with center
        uint64_t Vv[3][3], Lb[3][3], Rb[3][3];
        GATHER_W(Bt, lz, ly, w)
        uint64_t s = 0, c = 0;
#define ACC(bb) { uint64_t _b = (bb); c |= s & _b; s |= _b; }
#pragma unroll
        for (int dz = -1; dz <= 1; ++dz)
#pragma unroll
          for (int dy = -1; dy <= 1; ++dy) {
            ACC(NB(dz,dy,-1)); ACC(NB(dz,dy,1));
            if (dz != 0 || dy != 0) ACC(NB(dz,dy,0));
          }
#undef ACC
        res = c;
      }
      Ge[base] = res;
    }
    __syncthreads();
    // persist core ge2 for the S2 kernel (state is monotone non-increasing,
    // so stale/garbage ge2 where center==0 is harmless)
    for (int ti = tid; ti < 8 * 8 * 3; ti += 256) {
      int w = ti % 3, r = ti / 3, iy = r % 8, iz = r / 8;
      gge[((n * 162 + gz0 + iz) * 162 + (gy0 + iy)) * 3 + w] =
          Ge[LADDR(4 + iz, 4 + iy) + w];
    }
  } else {
    // load iteration-start ge2, halo 3
    for (int ti = tid; ti < 14 * 14 * 3; ti += 256) {
      int w = ti % 3, r = ti / 3, iz = r % 14, iy = r / 14;
      int lz = 1 + iz, ly = 1 + iy;
      int z = gz0 - 4 + lz, y = gy0 - 4 + ly;
      uint64_t v = 0;
      if ((unsigned)z < 162u && (unsigned)y < 162u)
        v = gge[((n * 162 + z) * 162 + y) * 3 + w];
      Ge[LADDR(lz, ly) + w] = v;
    }
    __syncthreads();
  }

  // ---- 4 subfield passes, shrinking halo 3,2,1,0 ----
  const int PLZ[8] = {1,0,1,0,1,0,1,0};  // lz parity (xo=0 -> z even -> lz odd)
  const int PLY[8] = {1,1,0,0,1,1,0,0};  // ly parity
  for (int kk = 0; kk < 4; ++kk) {
    const int k = k0 + kk, h = 3 - kk;
    const uint64_t xmask = (k < 4) ? 0x5555555555555555ull : 0xAAAAAAAAAAAAAAAAull;
    const int lo = 4 - h, hi = 11 + h;
    const int slz = lo + ((lo ^ PLZ[k]) & 1);
    const int sly = lo + ((lo ^ PLY[k]) & 1);
    const int cntz = (hi - slz) / 2 + 1;
    const int cnty = (hi - sly) / 2 + 1;
    for (int ti = tid; ti < cntz * cnty * 3; ti += 256) {
      int w = ti % 3, r = ti / 3, iz = r % cntz, iy = r / cntz;
      int lz = slz + 2 * iz, ly = sly + 2 * iy;
      int base = LADDR(lz, ly) + w;
      uint64_t center = Bt[base];
      uint64_t active = center & xmask & Ge[base];
      if (active == 0ull) continue;
      uint64_t Vv[3][3], Lb[3][3], Rb[3][3];
      GATHER_W(Bt, lz, ly, w)

      // C6 exact 3-bit counter over the 6 faces
      uint64_t on = 0, tw = 0, fo = 0;
#define C6ADD(b) { uint64_t _u = on & (b); on ^= (b); uint64_t _v = tw & _u; tw ^= _u; fo |= _v; }
      C6ADD(NB(-1,0,0)) C6ADD(NB(1,0,0)) C6ADD(NB(0,-1,0))
      C6ADD(NB(0,1,0))  C6ADD(NB(0,0,-1)) C6ADD(NB(0,0,1))
#undef C6ADD
      uint64_t c6eq5 = fo & on & ~tw;
      uint64_t c6le4 = ~(fo & (on | tw));

      // carry-save ==1 detectors over 18 then 26 neighbors
      uint64_t s = 0, c2 = 0;
#define CS(b) { uint64_t _b = (b); c2 |= s & _b; s |= _b; }
      CS(NB(-1,0,0)) CS(NB(1,0,0)) CS(NB(0,-1,0)) CS(NB(0,1,0)) CS(NB(0,0,-1)) CS(NB(0,0,1))
      CS(NB(-1,-1,0)) CS(NB(-1,1,0)) CS(NB(-1,0,-1)) CS(NB(-1,0,1))
      CS(NB(1,-1,0))  CS(NB(1,1,0))  CS(NB(1,0,-1))  CS(NB(1,0,1))
      CS(NB(0,-1,-1)) CS(NB(0,-1,1)) CS(NB(0,1,-1))  CS(NB(0,1,1))
      uint64_t e18 = s & ~c2;
      CS(NB(-1,-1,-1)) CS(NB(-1,-1,1)) CS(NB(-1,1,-1)) CS(NB(-1,1,1))
      CS(NB(1,-1,-1))  CS(NB(1,-1,1))  CS(NB(1,1,-1))  CS(NB(1,1,1))
      uint64_t e26 = s & ~c2;
#undef CS

      // B: corner set with its 6 octant face/edge cells all clear
      uint64_t badB = 0;
#pragma unroll
      for (int sz = -1; sz <= 1; sz += 2)
#pragma unroll
        for (int sy = -1; sy <= 1; sy += 2)
#pragma unroll
          for (int sx = -1; sx <= 1; sx += 2) {
            uint64_t oct = NB(sz,0,0) | NB(0,sy,0) | NB(0,0,sx)
                         | NB(sz,sy,0) | NB(sz,0,sx) | NB(0,sy,sx);
            badB |= NB(sz,sy,sx) & ~oct;
          }
      uint64_t b0ok = ~badB;

      // A: face clear with its full 4-cell in-plane ring set
      uint64_t badA = 0;
      badA |= ~NB(-1,0,0) & NB(-1,-1,0) & NB(-1,1,0) & NB(-1,0,-1) & NB(-1,0,1);
      badA |= ~NB( 1,0,0) & NB( 1,-1,0) & NB( 1,1,0) & NB( 1,0,-1) & NB( 1,0,1);
      badA |= ~NB(0,-1,0) & NB(-1,-1,0) & NB(1,-1,0) & NB(0,-1,-1) & NB(0,-1,1);
      badA |= ~NB(0, 1,0) & NB(-1, 1,0) & NB(1, 1,0) & NB(0, 1,-1) & NB(0, 1,1);
      badA |= ~NB(0,0,-1) & NB(-1,0,-1) & NB(1,0,-1) & NB(0,-1,-1) & NB(0,1,-1);
      badA |= ~NB(0,0, 1) & NB(-1,0, 1) & NB(1,0, 1) & NB(0,-1, 1) & NB(0,1, 1);
      uint64_t a0ok = ~badA;

      uint64_t simple = c6eq5 | e26 | (e18 & b0ok) | (c6le4 & a0ok & b0ok);
      uint64_t del = simple & active;
      if (del) Bt[base] = center & ~del;
      // no same-pass task reads this word's updated-parity bits; u64 tearing
      // harmless (readers use only unchanged-parity bits) -- R5 argument
    }
    __syncthreads();
  }

  // ---- epilogue ----
  if (outf) {
    // final half-iteration: write float output for core directly from LDS
    for (int ti = tid; ti < 8 * 8 * 40; ti += 256) {
      int g = ti % 40, r = ti / 40, iy = r % 8, iz = r / 8;
      int base = LADDR(4 + iz, 4 + iy);
      int bi = 1 + 4 * g;                // padded x of first of 4 floats
      int wx = bi >> 6, sft = bi & 63;
      uint64_t v = Bt[base + wx] >> sft;
      if (sft > 60) v |= Bt[base + wx + 1] << (64 - sft);
      outf[((n * 160 + (gz0 + iz - 1)) * 160 + (gy0 + iy - 1)) * 40 + g] =
          make_float4((float)(v & 1u), (float)((v >> 1) & 1u),
                      (float)((v >> 2) & 1u), (float)((v >> 3) & 1u));
    }
  } else {
    // write core state words back (disjoint across blocks)
    for (int ti = tid; ti < 8 * 8 * 3; ti += 256) {
      int w = ti % 3, r = ti / 3, iy = r % 8, iz = r / 8;
      dst[((n * 162 + gz0 + iz) * 162 + (gy0 + iy)) * 3 + w] =
          Bt[LADDR(4 + iz, 4 + iy) + w];
    }
  }
}

// ---------------------------- launcher --------------------------------------
extern "C" void kernel_launch(void* const* d_in, const int* in_sizes, int n_in,
                              void* d_out, int out_size, void* d_ws, size_t ws_size,
                              hipStream_t stream) {
  const float* in = (const float*)d_in[0];
  float4* out = (float4*)d_out;
  uint64_t* A = (uint64_t*)d_ws;          // state buffer A
  uint64_t* B = A + NW;                   // state buffer B
  uint64_t* G = B + NW;                   // iteration-start ge2

  k_binarize<<<dim3(2 * PDIM * PDIM), dim3(192), 0, stream>>>(in, A);
  for (int it = 0; it < 5; ++it) {
    k_half<<<dim3(800), dim3(256), 0, stream>>>(A, B, G, nullptr, 0, it == 0 ? 1 : 0);
    k_half<<<dim3(800), dim3(256), 0, stream>>>(B, A, G,
        (it == 4) ? out : nullptr, 4, 0);
  }
}

// Round 11
// 228.705 us; speedup vs baseline: 1.5115x; 1.1964x over previous
//
#include <hip/hip_runtime.h>
#include <stdint.h>

// No implicit FMA contraction: the JAX eager reference has none across ops;
// where XLA fuses we write fmaf() explicitly.
#pragma clang fp contract(off)

#define PDIM 162
#define NW   (2*PDIM*PDIM*3)   // 157464 words, 1.26 MB per bitboard
#define NWH  (NW/2)            // 78732
#define OD   160

// LDS tile: 32 z-rows x 32 y-rows x 3 words, addr lz*97 + ly*3 + w.
// 97 u64 = 194 dwords == 2 mod 32. ge2 lane stride (Dly=1 -> 6 dwords) walks
// 16 banks (conflict-free, 3-lane broadcast groups); subfield (Dly=2 -> 12
// dwords) ~3-way on a minority of accesses. Fixes R6's 8-way (LSTR=4) layout.
#define PZ 97
#define LADDR(lz,ly) ((lz)*PZ + (ly)*3)

// ---------------- threefry2x32, JAX partitionable scheme --------------------
__device__ __forceinline__ uint32_t rotl32(uint32_t x, uint32_t r) {
  return (x << r) | (x >> (32u - r));
}

__device__ __forceinline__ uint32_t threefry_bits(uint32_t idx) {
  const uint32_t ks0 = 0u, ks1 = 42u, ks2 = 0x1BD11BDAu ^ 0u ^ 42u;
  uint32_t x0 = 0u + ks0;
  uint32_t x1 = idx + ks1;
#define TFR(r) { x0 += x1; x1 = rotl32(x1, (r)); x1 ^= x0; }
  TFR(13u) TFR(15u) TFR(26u) TFR(6u)
  x0 += ks1; x1 += ks2 + 1u;
  TFR(17u) TFR(29u) TFR(16u) TFR(24u)
  x0 += ks2; x1 += ks0 + 2u;
  TFR(13u) TFR(15u) TFR(26u) TFR(6u)
  x0 += ks0; x1 += ks1 + 3u;
  TFR(17u) TFR(29u) TFR(16u) TFR(24u)
  x0 += ks1; x1 += ks2 + 4u;
  TFR(13u) TFR(15u) TFR(26u) TFR(6u)
  x0 += ks2; x1 += ks0 + 5u;
#undef TFR
  return x0 ^ x1;
}

// ------------- XLA-CPU (Cephes) float32 log replication ---------------------
__device__ __forceinline__ float xla_logf(float xin) {
  uint32_t bits = __float_as_uint(xin);
  float e = (float)((int)(bits >> 23) - 126);
  float x = __uint_as_float((bits & 0x007fffffu) | 0x3f000000u);
  const float SQRTHF = 0.707106781186547524f;
  bool lt = (x < SQRTHF);
  float tmp = lt ? x : 0.0f;
  e = e - (lt ? 1.0f : 0.0f);
  x = x - 1.0f;
  x = x + tmp;
  float z = x * x;
  float y = 7.0376836292e-2f;
  y = fmaf(y, x, -1.1514610310e-1f);
  y = fmaf(y, x,  1.1676998740e-1f);
  y = fmaf(y, x, -1.2420140846e-1f);
  y = fmaf(y, x,  1.4249322787e-1f);
  y = fmaf(y, x, -1.6668057665e-1f);
  y = fmaf(y, x,  2.0000714765e-1f);
  y = fmaf(y, x, -2.4999993993e-1f);
  y = fmaf(y, x,  3.3333331174e-1f);
  y = y * x;
  y = y * z;
  y = fmaf(e, -2.12194440e-4f, y);
  y = fmaf(-0.5f, z, y);
  x = x + y;
  x = fmaf(e, 0.693359375f, x);
  return x;
}

__device__ __forceinline__ float xla_log1pf(float x) {
  float for_large = xla_logf(x + 1.0f);
  float for_small = fmaf(-0.5f, x, 1.0f) * x;
  return (fabsf(x) < 1e-4f) ? for_small : for_large;
}

// one voxel's decision (exact JAX/XLA bit replication)
__device__ __forceinline__ bool bin_pred(const float* __restrict__ in, uint32_t w,
                                         uint32_t lane) {
  uint32_t row = w / 3u, wx = w - row * 3u;
  uint32_t n  = row / (uint32_t)(PDIM * PDIM);
  uint32_t rr = row - n * (uint32_t)(PDIM * PDIM);
  uint32_t z  = rr / (uint32_t)PDIM;
  uint32_t y  = rr - z * (uint32_t)PDIM;
  uint32_t x  = wx * 64u + lane;
  // pad voxels are provably 0: |0.33*noise| <= 6.08 < 18.42 = |log alpha(0)|
  if ((z - 1u) >= 160u || (y - 1u) >= 160u || (x - 1u) >= 160u) return false;
  float v = in[((n * 160u + (z - 1u)) * 160u + (y - 1u)) * 160u + (x - 1u)];
  uint32_t i = row * 162u + x;            // flat padded index for RNG
  uint32_t b = threefry_bits(i);
  float f  = __uint_as_float((b >> 9) | 0x3f800000u) - 1.0f;
  float uu = fmaxf(1e-8f, f + 1e-8f);
  float la = xla_logf((v + 1e-8f) / ((1.0f - v) + 1e-8f));
  float noise = xla_logf(uu) - xla_log1pf(-uu);
  float zs = la + noise * 0.33f;
  return (zs > 1.1920928955078125e-7f);   // logistic>0.5 iff z>2^-23
}

// ---------------------------- binarize --------------------------------------
// ILP-2: each wave produces TWO words (w and w+NW/2); the two independent
// threefry+log chains interleave to fill the serial-dependency bubbles.
__global__ __launch_bounds__(256) void k_binarize(const float* __restrict__ in,
                                                  uint64_t* __restrict__ bits) {
  uint32_t t = blockIdx.x * 256u + threadIdx.x;
  uint32_t w0 = t >> 6, lane = t & 63u;
  if (w0 >= (uint32_t)NWH) return;        // wave-uniform
  uint32_t w1 = w0 + (uint32_t)NWH;
  bool p0 = bin_pred(in, w0, lane);
  bool p1 = bin_pred(in, w1, lane);
  uint64_t m0 = __ballot(p0);
  uint64_t m1 = __ballot(p1);
  if (lane == 0) { bits[w0] = m0; bits[w1] = m1; }
}

// ------------- per-word neighborhood from LDS row triples -------------------
#define NB(dz,dy,dx) ((dx)==-1 ? Lb[(dz)+1][(dy)+1] : ((dx)==1 ? Rb[(dz)+1][(dy)+1] : Vv[(dz)+1][(dy)+1]))

#define GATHER_W(SRC, lz, ly, w) \
  _Pragma("unroll") \
  for (int dz = 0; dz < 3; ++dz) \
    _Pragma("unroll") \
    for (int dy = 0; dy < 3; ++dy) { \
      int rb = LADDR((lz) + dz - 1, (ly) + dy - 1); \
      uint64_t r0 = SRC[rb], r1 = SRC[rb + 1], r2 = SRC[rb + 2]; \
      uint64_t b = ((w) == 0) ? r0 : (((w) == 1) ? r1 : r2); \
      uint64_t a = ((w) == 0) ? 0ull : (((w) == 1) ? r0 : r1); \
      uint64_t d = ((w) == 0) ? r1 : (((w) == 1) ? r2 : 0ull); \
      Vv[dz][dy] = b; \
      Lb[dz][dy] = (b << 1) | (a >> 63); \
      Rb[dz][dy] = (b >> 1) | (d << 63); \
    }

// ---------------------------- iteration kernel ------------------------------
// One block: 16x16 (z,y) core x full 192-bit x, halo 8 -> 32x32 LDS tile.
// ge2 on halo 7, then 8 subfield passes with shrinking halo; writes core only
// (or, final iteration, the float output directly from LDS).
__global__ __launch_bounds__(1024) void k_iter(const uint64_t* __restrict__ bin,
                                               uint64_t* __restrict__ bout,
                                               float4* __restrict__ outf,
                                               int zero_pads) {
  __shared__ uint64_t Bt[32 * PZ];
  __shared__ uint64_t Ge[32 * PZ];
  const int tid = threadIdx.x;
  const int bid = blockIdx.x;
  const int n  = bid / 100;
  const int rm = bid - n * 100;
  const int tz = rm / 10, ty = rm - tz * 10;
  const int gz0 = 1 + 16 * tz, gy0 = 1 + 16 * ty;   // both odd

  // Zero bout's pad rows (z or y in {0,161}) once per replay (block 0, iter 1).
  if (zero_pads && bid == 0) {
    for (int j = tid; j < 1288; j += 1024) {
      int nn, z, y;
      if (j < 648) { nn = j / 324; int r = j - nn * 324;
                     z = (r >= 162) ? 161 : 0; y = (r >= 162) ? r - 162 : r; }
      else { int j2 = j - 648; nn = j2 / 320; int r = j2 - nn * 320;
             y = (r >= 160) ? 161 : 0; z = 1 + ((r >= 160) ? r - 160 : r); }
      uint64_t* p = bout + (((nn * 162 + z) * 162) + y) * 3;
      p[0] = 0; p[1] = 0; p[2] = 0;
    }
  }

  // ---- load tile + halo 8 (w,ly fastest -> coalesced global reads) ----
  for (int ti = tid; ti < 32 * 32 * 3; ti += 1024) {
    int w = ti % 3, r = ti / 3, ly = r % 32, lz = r / 32;
    int z = gz0 - 8 + lz, y = gy0 - 8 + ly;
    uint64_t v = 0;
    if ((unsigned)z < 162u && (unsigned)y < 162u)
      v = bin[((n * 162 + z) * 162 + y) * 3 + w];
    Bt[LADDR(lz, ly) + w] = v;
  }
  __syncthreads();

  // ---- ge2 (C26>=2, not-endpoint) on halo 7 (30x30), iteration-start state
  for (int ti = tid; ti < 30 * 30 * 3; ti += 1024) {
    int w = ti % 3, r = ti / 3, iy = r % 30, iz = r / 30;
    int lz = 1 + iz, ly = 1 + iy;
    int base = LADDR(lz, ly) + w;
    uint64_t res = 0;
    if (Bt[base] != 0ull) {               // ge2 only consumed ANDed with center
      uint64_t Vv[3][3], Lb[3][3], Rb[3][3];
      GATHER_W(Bt, lz, ly, w)
      uint64_t s = 0, c = 0;
#define ACC(bb) { uint64_t _b = (bb); c |= s & _b; s |= _b; }
#pragma unroll
      for (int dz = -1; dz <= 1; ++dz)
#pragma unroll
        for (int dy = -1; dy <= 1; ++dy) {
          ACC(NB(dz,dy,-1)); ACC(NB(dz,dy,1));
          if (dz != 0 || dy != 0) ACC(NB(dz,dy,0));
        }
#undef ACC
      res = c;
    }
    Ge[base] = res;
  }
  __syncthreads();

  // ---- 8 subfield passes, halo 7-k, parity per reference offsets order ----
  const int PLZ[8] = {1,0,1,0,1,0,1,0};   // lz parity (xo=0 -> z even -> lz odd)
  const int PLY[8] = {1,1,0,0,1,1,0,0};   // ly parity
  for (int k = 0; k < 8; ++k) {
    const int h = 7 - k, cnt1 = 8 + h;
    const uint64_t xmask = (k < 4) ? 0x5555555555555555ull : 0xAAAAAAAAAAAAAAAAull;
    int s0 = 8 - h;
    const int slz = s0 + ((s0 ^ PLZ[k]) & 1);
    const int sly = s0 + ((s0 ^ PLY[k]) & 1);
    for (int ti = tid; ti < cnt1 * cnt1 * 3; ti += 1024) {
      int w = ti % 3, r = ti / 3, iy = r % cnt1, iz = r / cnt1;
      int lz = slz + 2 * iz, ly = sly + 2 * iy;
      int base = LADDR(lz, ly) + w;
      uint64_t center = Bt[base];
      uint64_t active = center & xmask & Ge[base];
      if (active == 0ull) continue;
      uint64_t Vv[3][3], Lb[3][3], Rb[3][3];
      GATHER_W(Bt, lz, ly, w)

      // C6 exact 3-bit counter over the 6 faces
      uint64_t on = 0, tw = 0, fo = 0;
#define C6ADD(b) { uint64_t _u = on & (b); on ^= (b); uint64_t _v = tw & _u; tw ^= _u; fo |= _v; }
      C6ADD(NB(-1,0,0)) C6ADD(NB(1,0,0)) C6ADD(NB(0,-1,0))
      C6ADD(NB(0,1,0))  C6ADD(NB(0,0,-1)) C6ADD(NB(0,0,1))
#undef C6ADD
      uint64_t c6eq5 = fo & on & ~tw;
      uint64_t c6le4 = ~(fo & (on | tw));

      // carry-save ==1 detectors over 18 then 26 neighbors
      uint64_t s = 0, c2 = 0;
#define CS(b) { uint64_t _b = (b); c2 |= s & _b; s |= _b; }
      CS(NB(-1,0,0)) CS(NB(1,0,0)) CS(NB(0,-1,0)) CS(NB(0,1,0)) CS(NB(0,0,-1)) CS(NB(0,0,1))
      CS(NB(-1,-1,0)) CS(NB(-1,1,0)) CS(NB(-1,0,-1)) CS(NB(-1,0,1))
      CS(NB(1,-1,0))  CS(NB(1,1,0))  CS(NB(1,0,-1))  CS(NB(1,0,1))
      CS(NB(0,-1,-1)) CS(NB(0,-1,1)) CS(NB(0,1,-1))  CS(NB(0,1,1))
      uint64_t e18 = s & ~c2;
      CS(NB(-1,-1,-1)) CS(NB(-1,-1,1)) CS(NB(-1,1,-1)) CS(NB(-1,1,1))
      CS(NB(1,-1,-1))  CS(NB(1,-1,1))  CS(NB(1,1,-1))  CS(NB(1,1,1))
      uint64_t e26 = s & ~c2;
#undef CS

      // B: corner set with its 6 octant face/edge cells all clear
      uint64_t badB = 0;
#pragma unroll
      for (int sz = -1; sz <= 1; sz += 2)
#pragma unroll
        for (int sy = -1; sy <= 1; sy += 2)
#pragma unroll
          for (int sx = -1; sx <= 1; sx += 2) {
            uint64_t oct = NB(sz,0,0) | NB(0,sy,0) | NB(0,0,sx)
                         | NB(sz,sy,0) | NB(sz,0,sx) | NB(0,sy,sx);
            badB |= NB(sz,sy,sx) & ~oct;
          }
      uint64_t b0ok = ~badB;

      // A: face clear with its full 4-cell in-plane ring set
      uint64_t badA = 0;
      badA |= ~NB(-1,0,0) & NB(-1,-1,0) & NB(-1,1,0) & NB(-1,0,-1) & NB(-1,0,1);
      badA |= ~NB( 1,0,0) & NB( 1,-1,0) & NB( 1,1,0) & NB( 1,0,-1) & NB( 1,0,1);
      badA |= ~NB(0,-1,0) & NB(-1,-1,0) & NB(1,-1,0) & NB(0,-1,-1) & NB(0,-1,1);
      badA |= ~NB(0, 1,0) & NB(-1, 1,0) & NB(1, 1,0) & NB(0, 1,-1) & NB(0, 1,1);
      badA |= ~NB(0,0,-1) & NB(-1,0,-1) & NB(1,0,-1) & NB(0,-1,-1) & NB(0,1,-1);
      badA |= ~NB(0,0, 1) & NB(-1,0, 1) & NB(1,0, 1) & NB(0,-1, 1) & NB(0,1, 1);
      uint64_t a0ok = ~badA;

      uint64_t simple = c6eq5 | e26 | (e18 & b0ok) | (c6le4 & a0ok & b0ok);
      uint64_t del = simple & active;
      if (del) Bt[base] = center & ~del;
      // readers only consume non-updated-parity bits; tearing-safe (R5 arg)
    }
    __syncthreads();
  }

  // ---- epilogue ----
  if (outf) {
    // final iteration: write float output for core directly from LDS
    for (int ti = tid; ti < 16 * 16 * 40; ti += 1024) {
      int g = ti % 40, r = ti / 40, iy = r % 16, iz = r / 16;
      int base = LADDR(8 + iz, 8 + iy);
      int bi = 1 + 4 * g;                 // padded x of first of 4 floats
      int wx = bi >> 6, sft = bi & 63;
      uint64_t v = Bt[base + wx] >> sft;
      if (sft > 60) v |= Bt[base + wx + 1] << (64 - sft);
      outf[((n * 160 + (gz0 + iz - 1)) * 160 + (gy0 + iy - 1)) * 40 + g] =
          make_float4((float)(v & 1u), (float)((v >> 1) & 1u),
                      (float)((v >> 2) & 1u), (float)((v >> 3) & 1u));
    }
  } else {
    // write core words back (disjoint across blocks)
    for (int ti = tid; ti < 16 * 16 * 3; ti += 1024) {
      int w = ti % 3, r = ti / 3, iy = r % 16, iz = r / 16;
      bout[((n * 162 + gz0 + iz) * 162 + (gy0 + iy)) * 3 + w] =
          Bt[LADDR(8 + iz, 8 + iy) + w];
    }
  }
}

// ---------------------------- launcher --------------------------------------
extern "C" void kernel_launch(void* const* d_in, const int* in_sizes, int n_in,
                              void* d_out, int out_size, void* d_ws, size_t ws_size,
                              hipStream_t stream) {
  const float* in = (const float*)d_in[0];
  float4* out = (float4*)d_out;
  uint64_t* A = (uint64_t*)d_ws;          // bitboard A
  uint64_t* B = A + NW;                   // bitboard B

  k_binarize<<<dim3((NWH * 64 + 255) / 256), dim3(256), 0, stream>>>(in, A);
  k_iter<<<dim3(200), dim3(1024), 0, stream>>>(A, B, nullptr, 1); // iter 1
  k_iter<<<dim3(200), dim3(1024), 0, stream>>>(B, A, nullptr, 0); // iter 2
  k_iter<<<dim3(200), dim3(1024), 0, stream>>>(A, B, nullptr, 0); // iter 3
  k_iter<<<dim3(200), dim3(1024), 0, stream>>>(B, A, nullptr, 0); // iter 4
  k_iter<<<dim3(200), dim3(1024), 0, stream>>>(A, nullptr, out, 0); // iter 5 -> out
}